// Round 6
// baseline (52.983 us; speedup 1.0000x reference)
//
#include <hip/hip_runtime.h>
#include <hip/hip_bf16.h>
#include <stdint.h>

// Problem dims (fixed by reference)
#define D_DIM    768
#define K_STATES 128
#define M_ROWS   65536      // B*T = 256*256
#define BM       64         // rows per block
#define BK       32         // D-chunk per K-step
#define NSTEPS   (D_DIM / BK)   // 24
#define LDSTRIDE 40         // bf16 elems per LDS row: 80B, 16B-aligned, 2-way-max banks

typedef __attribute__((ext_vector_type(8))) short bf16x8;
typedef __attribute__((ext_vector_type(4))) float f32x4;
typedef __attribute__((ext_vector_type(4))) int   i32x4;

// Single fused kernel: out[bt][k] = cross + c[k] - 0.5*s2[bt]
// R1 skeleton (depth-1 reg prefetch -> LDS dbuf, 1 barrier/step, 4 waves of
// 32x64, grid=1024, 4 blocks/CU pinned) with B converted per-step from f32
// means (L2-resident; each mean element converted once per block) and
// c[k] = -0.5*(D*log2pi + sum(log var) + m2[k]) computed in-block.
__global__ void __launch_bounds__(256, 4) dmv_fused(
        const float* __restrict__ s, const float* __restrict__ means,
        const float* __restrict__ var, float* __restrict__ out) {
    __shared__ unsigned short As[2][BM * LDSTRIDE];        // 2 x 5.0 KB
    __shared__ unsigned short Bs[2][K_STATES * LDSTRIDE];  // 2 x 10.0 KB
    __shared__ float ivs[D_DIM];                           // 3 KB
    __shared__ float part[BM][8];
    __shared__ float s2row[BM];
    __shared__ float cs[K_STATES];
    __shared__ float rlg[4];

    const int t    = threadIdx.x;
    const int lane = t & 63;
    const int w    = t >> 6;
    const int wr   = w >> 1;
    const int wc   = w & 1;
    const long rowBase = (long)blockIdx.x * BM;

    // ivs + per-block sum(log var)
    float ldp = 0.f;
    for (int d = t; d < D_DIM; d += 256) {
        float v = var[d];
        ivs[d] = 1.0f / v;
        ldp += logf(v);
    }
#pragma unroll
    for (int off = 32; off > 0; off >>= 1) ldp += __shfl_down(ldp, off, 64);
    if ((t & 63) == 0) rlg[t >> 6] = ldp;

    // staging geometry per K-step:
    // A (64x32 f32): row = j*32 + (t>>3), cols (t&7)*4 .. +3   (2 x f32x4/thread)
    // B (128x32 f32 means): row = t>>1, cols (t&1)*16 + 0..15  (4 x f32x4/thread)
    const int arow0 = t >> 3;
    const int acol  = (t & 7) * 4;
    const int brow  = t >> 1;
    const int bcol0 = (t & 1) * 16;

    const float* sA = s     + (rowBase + arow0) * D_DIM + acol;
    const float* sM = means + brow * D_DIM + bcol0;

    f32x4 aP[2];
    f32x4 bP[4];
    float s2acc[2] = {0.f, 0.f};
    float m2p = 0.f;

    f32x4 acc[2][4];
#pragma unroll
    for (int i = 0; i < 2; ++i)
#pragma unroll
        for (int j = 0; j < 4; ++j) acc[i][j] = f32x4{0.f, 0.f, 0.f, 0.f};

#define LOADP(ST) do {                                                         \
    aP[0] = *(const f32x4*)(sA + (ST) * BK);                                   \
    aP[1] = *(const f32x4*)(sA + (long)32 * D_DIM + (ST) * BK);                \
    bP[0] = *(const f32x4*)(sM + (ST) * BK);                                   \
    bP[1] = *(const f32x4*)(sM + (ST) * BK + 4);                               \
    bP[2] = *(const f32x4*)(sM + (ST) * BK + 8);                               \
    bP[3] = *(const f32x4*)(sM + (ST) * BK + 12);                              \
} while (0)

#define STAGE(BUF, K0) do {                                                    \
    /* A: f32 -> bf16 + s2 accumulation */                                     \
    f32x4 ivv = *reinterpret_cast<const f32x4*>(&ivs[(K0) + acol]);            \
    _Pragma("unroll")                                                          \
    for (int j = 0; j < 2; ++j) {                                              \
        const int row = j * 32 + arow0;                                        \
        f32x4 v = aP[j];                                                       \
        s2acc[j] += v[0]*v[0]*ivv[0] + v[1]*v[1]*ivv[1]                        \
                  + v[2]*v[2]*ivv[2] + v[3]*v[3]*ivv[3];                       \
        union { uint2 u2; __hip_bfloat162 h[2]; } pk;                          \
        pk.h[0] = __float22bfloat162_rn(make_float2(v[0], v[1]));              \
        pk.h[1] = __float22bfloat162_rn(make_float2(v[2], v[3]));              \
        *reinterpret_cast<uint2*>(&As[BUF][row * LDSTRIDE + acol]) = pk.u2;    \
    }                                                                          \
    /* B: means*iv -> bf16 + m2 accumulation (16 elems/thread) */              \
    {                                                                          \
        union { i32x4 i4; __hip_bfloat162 h[4]; } q0, q1;                      \
        _Pragma("unroll")                                                      \
        for (int j = 0; j < 4; ++j) {                                          \
            f32x4 iw = *reinterpret_cast<const f32x4*>(&ivs[(K0) + bcol0 + j*4]);\
            f32x4 mv = bP[j];                                                  \
            m2p += mv[0]*mv[0]*iw[0] + mv[1]*mv[1]*iw[1]                       \
                 + mv[2]*mv[2]*iw[2] + mv[3]*mv[3]*iw[3];                      \
            __hip_bfloat162 plo = __float22bfloat162_rn(                       \
                make_float2(mv[0]*iw[0], mv[1]*iw[1]));                        \
            __hip_bfloat162 phi = __float22bfloat162_rn(                       \
                make_float2(mv[2]*iw[2], mv[3]*iw[3]));                        \
            if (j < 2) { q0.h[(j&1)*2] = plo; q0.h[(j&1)*2+1] = phi; }         \
            else       { q1.h[(j&1)*2] = plo; q1.h[(j&1)*2+1] = phi; }         \
        }                                                                      \
        *reinterpret_cast<i32x4*>(&Bs[BUF][brow * LDSTRIDE + bcol0])     = q0.i4;\
        *reinterpret_cast<i32x4*>(&Bs[BUF][brow * LDSTRIDE + bcol0 + 8]) = q1.i4;\
    }                                                                          \
} while (0)

    const int g  = (lane >> 4) * 8;
    const int rA = wr * 32 + (lane & 15);
    const int rB = wc * 64 + (lane & 15);

#define COMPUTE(BUF) do {                                                      \
    const unsigned short* Ab = &As[BUF][0];                                    \
    const unsigned short* Bb = &Bs[BUF][0];                                    \
    bf16x8 afrag[2], bfrag[4];                                                 \
    _Pragma("unroll")                                                          \
    for (int i = 0; i < 2; ++i)                                                \
        afrag[i] = *(const bf16x8*)(Ab + (rA + i * 16) * LDSTRIDE + g);        \
    _Pragma("unroll")                                                          \
    for (int j = 0; j < 4; ++j)                                                \
        bfrag[j] = *(const bf16x8*)(Bb + (rB + j * 16) * LDSTRIDE + g);        \
    _Pragma("unroll")                                                          \
    for (int i = 0; i < 2; ++i)                                                \
        _Pragma("unroll")                                                      \
        for (int j = 0; j < 4; ++j)                                            \
            acc[i][j] = __builtin_amdgcn_mfma_f32_16x16x32_bf16(               \
                            afrag[i], bfrag[j], acc[i][j], 0, 0, 0);           \
} while (0)

    // prologue (R1 cadence): stage step 0, then loop
    LOADP(0);
    __syncthreads();               // ivs / rlg ready
    const float slog = rlg[0] + rlg[1] + rlg[2] + rlg[3];
    STAGE(0, 0);

    for (int st = 0; st < NSTEPS; ++st) {
        const int cur = st & 1;
        if (st + 1 < NSTEPS) LOADP(st + 1);
        __syncthreads();           // buf[cur] staged & prior reads drained
        COMPUTE(cur);
        if (st + 1 < NSTEPS) STAGE(st + 1 & 1, (st + 1) * BK);
    }

    // per-state constant c[k]: pair (t, t^1) share row brow
#pragma unroll
    for (int j = 0; j < 2; ++j) part[j * 32 + arow0][t & 7] = s2acc[j];
    {
        float m2t = m2p + __shfl_xor(m2p, 1, 64);
        if (!(t & 1))
            cs[brow] = -0.5f * ((float)D_DIM * 1.8378770664093453f + slog + m2t);
    }
    __syncthreads();
    if (t < BM) {
        float v = 0.f;
#pragma unroll
        for (int sl = 0; sl < 8; ++sl) v += part[t][sl];
        s2row[t] = v;
    }
    __syncthreads();

    // epilogue: C/D layout col = lane&15, row = (lane>>4)*4 + reg [m89/m91]
    const int colBase = wc * 64 + (lane & 15);
#pragma unroll
    for (int i = 0; i < 2; ++i) {
        const int rl0 = wr * 32 + i * 16 + (lane >> 4) * 4;
#pragma unroll
        for (int j = 0; j < 4; ++j) {
            const int col = colBase + j * 16;
            const float cj = cs[col];
#pragma unroll
            for (int r = 0; r < 4; ++r) {
                const int rl = rl0 + r;
                out[(rowBase + rl) * K_STATES + col] = acc[i][j][r] + cj - 0.5f * s2row[rl];
            }
        }
    }
#undef LOADP
#undef STAGE
#undef COMPUTE
}

extern "C" void kernel_launch(void* const* d_in, const int* in_sizes, int n_in,
                              void* d_out, int out_size, void* d_ws, size_t ws_size,
                              hipStream_t stream) {
    const float* s     = (const float*)d_in[0];
    const float* means = (const float*)d_in[1];
    const float* var   = (const float*)d_in[2];
    float* out = (float*)d_out;

    dmv_fused<<<M_ROWS / BM, 256, 0, stream>>>(s, means, var, out);
}

// Round 7
// 48.332 us; speedup vs baseline: 1.0962x; 1.0962x over previous
//
#include <hip/hip_runtime.h>
#include <hip/hip_bf16.h>
#include <stdint.h>

// Problem dims (fixed by reference)
#define D_DIM    768
#define K_STATES 128
#define M_ROWS   65536      // B*T = 256*256
#define BM       64         // rows per block
#define BK       64         // D-chunk per K-step (halves barrier count vs BK=32)
#define NSTEPS   (D_DIM / BK)   // 12
#define LDSTRIDE 72         // bf16 elems per LDS row: 144B, 16B-aligned, +4-bank row shift

typedef __attribute__((ext_vector_type(8))) short bf16x8;
typedef __attribute__((ext_vector_type(4))) float f32x4;
typedef __attribute__((ext_vector_type(4))) int   i32x4;

__device__ __forceinline__ unsigned short f2bf(float f) {
    union { float f; unsigned u; } x; x.f = f;
    unsigned r = (x.u + 0x7FFFu + ((x.u >> 16) & 1u)) >> 16;   // RNE
    return (unsigned short)r;
}

// ---------------- prep: mw[k][d] = means*inv_var (bf16), c[k] = log_norm - 0.5*m2[k]
__global__ void __launch_bounds__(256) prep_kernel(
        const float* __restrict__ means, const float* __restrict__ var,
        unsigned short* __restrict__ mwbf, float* __restrict__ cvec) {
    const int k = blockIdx.x;
    const int t = threadIdx.x;
    float m2 = 0.f, ld = 0.f;
    for (int d = t; d < D_DIM; d += 256) {
        float v  = var[d];
        float iv = 1.0f / v;
        float m  = means[k * D_DIM + d];
        mwbf[k * D_DIM + d] = f2bf(m * iv);
        m2 += m * m * iv;
        ld += logf(v);
    }
#pragma unroll
    for (int off = 32; off > 0; off >>= 1) {
        m2 += __shfl_down(m2, off, 64);
        ld += __shfl_down(ld, off, 64);
    }
    __shared__ float rm[4], rl[4];
    const int wid = t >> 6;
    if ((t & 63) == 0) { rm[wid] = m2; rl[wid] = ld; }
    __syncthreads();
    if (t == 0) {
        float M2 = rm[0] + rm[1] + rm[2] + rm[3];
        float LD = rl[0] + rl[1] + rl[2] + rl[3];
        cvec[k] = -0.5f * ((float)D_DIM * 1.8378770664093453f + LD + M2);
    }
}

// ---------------- main: R1 skeleton, BK=64 -> 12 barriers instead of 24.
// Block: 64 rows x 128 states, 4 waves each 32x64 (acc[2][4], 2 k-subs/step),
// grid = 1024, 2 blocks/CU (LDS ~59KB). Depth-1 reg prefetch -> LDS dbuf,
// ONE barrier per K-step.
__global__ void __launch_bounds__(256, 2) dmv_main(
        const float* __restrict__ s, const unsigned short* __restrict__ mwbf,
        const float* __restrict__ var, const float* __restrict__ cvec,
        float* __restrict__ out) {
    __shared__ unsigned short As[2][BM * LDSTRIDE];        // 2 x 9.0 KB
    __shared__ unsigned short Bs[2][K_STATES * LDSTRIDE];  // 2 x 18.0 KB
    __shared__ float ivs[D_DIM];                           // 3 KB
    __shared__ float part[BM][4];
    __shared__ float s2row[BM];
    __shared__ float cs[K_STATES];

    const int t    = threadIdx.x;
    const int lane = t & 63;
    const int w    = t >> 6;
    const int wr   = w >> 1;
    const int wc   = w & 1;
    const long rowBase = (long)blockIdx.x * BM;

    for (int d = t; d < D_DIM; d += 256) ivs[d] = 1.0f / var[d];
    if (t < K_STATES) cs[t] = cvec[t];

    // staging geometry per K-step (BK=64):
    // A (64x64 f32):  row = t>>2, col base (t&3)*4, loads at +j*16 (4 x f32x4)
    // B (128x64 bf16): row = t>>1, col base (t&1)*32, loads at +j*8 (4 x i32x4)
    const int arow = t >> 2;
    const int acol = (t & 3) * 4;
    const int brow = t >> 1;
    const int bcol = (t & 1) * 32;

    const float*          sA = s    + (rowBase + arow) * D_DIM + acol;
    const unsigned short* sB = mwbf + brow * D_DIM + bcol;

    f32x4 aP[4];
    i32x4 bP[4];
    float s2acc = 0.f;

    f32x4 acc[2][4];
#pragma unroll
    for (int i = 0; i < 2; ++i)
#pragma unroll
        for (int j = 0; j < 4; ++j) acc[i][j] = f32x4{0.f, 0.f, 0.f, 0.f};

#define LOADP(ST) do {                                                         \
    _Pragma("unroll")                                                          \
    for (int j = 0; j < 4; ++j)                                                \
        aP[j] = *(const f32x4*)(sA + (ST) * BK + j * 16);                      \
    _Pragma("unroll")                                                          \
    for (int j = 0; j < 4; ++j)                                                \
        bP[j] = *(const i32x4*)(sB + (ST) * BK + j * 8);                       \
} while (0)

#define STAGE(BUF, K0) do {                                                    \
    _Pragma("unroll")                                                          \
    for (int j = 0; j < 4; ++j) {                                              \
        f32x4 ivv = *reinterpret_cast<const f32x4*>(&ivs[(K0) + j * 16 + acol]);\
        f32x4 v = aP[j];                                                       \
        s2acc += v[0]*v[0]*ivv[0] + v[1]*v[1]*ivv[1]                           \
               + v[2]*v[2]*ivv[2] + v[3]*v[3]*ivv[3];                          \
        union { uint2 u2; __hip_bfloat162 h[2]; } pk;                          \
        pk.h[0] = __float22bfloat162_rn(make_float2(v[0], v[1]));              \
        pk.h[1] = __float22bfloat162_rn(make_float2(v[2], v[3]));              \
        *reinterpret_cast<uint2*>(&As[BUF][arow * LDSTRIDE + j * 16 + acol])   \
            = pk.u2;                                                           \
    }                                                                          \
    _Pragma("unroll")                                                          \
    for (int j = 0; j < 4; ++j)                                                \
        *reinterpret_cast<i32x4*>(&Bs[BUF][brow * LDSTRIDE + bcol + j * 8])    \
            = bP[j];                                                           \
} while (0)

    const int g  = (lane >> 4) * 8;
    const int rA = wr * 32 + (lane & 15);
    const int rB = wc * 64 + (lane & 15);

#define COMPUTE(BUF) do {                                                      \
    const unsigned short* Ab = &As[BUF][0];                                    \
    const unsigned short* Bb = &Bs[BUF][0];                                    \
    _Pragma("unroll")                                                          \
    for (int ks = 0; ks < 2; ++ks) {                                           \
        bf16x8 afrag[2], bfrag[4];                                             \
        _Pragma("unroll")                                                      \
        for (int i = 0; i < 2; ++i)                                            \
            afrag[i] = *(const bf16x8*)(Ab + (rA + i * 16) * LDSTRIDE          \
                                           + ks * 32 + g);                     \
        _Pragma("unroll")                                                      \
        for (int j = 0; j < 4; ++j)                                            \
            bfrag[j] = *(const bf16x8*)(Bb + (rB + j * 16) * LDSTRIDE          \
                                           + ks * 32 + g);                     \
        _Pragma("unroll")                                                      \
        for (int i = 0; i < 2; ++i)                                            \
            _Pragma("unroll")                                                  \
            for (int j = 0; j < 4; ++j)                                        \
                acc[i][j] = __builtin_amdgcn_mfma_f32_16x16x32_bf16(           \
                                afrag[i], bfrag[j], acc[i][j], 0, 0, 0);       \
    }                                                                          \
} while (0)

    // prologue (R1 cadence): stage step 0, then loop
    LOADP(0);
    __syncthreads();               // ivs/cs ready
    STAGE(0, 0);

    for (int st = 0; st < NSTEPS; ++st) {
        const int cur = st & 1;
        if (st + 1 < NSTEPS) LOADP(st + 1);
        __syncthreads();           // buf[cur] staged & prior reads drained
        COMPUTE(cur);
        if (st + 1 < NSTEPS) STAGE((st + 1) & 1, (st + 1) * BK);
    }

    // s2 reduction: thread owns row arow, col-slot t&3
    part[arow][t & 3] = s2acc;
    __syncthreads();
    if (t < BM)
        s2row[t] = part[t][0] + part[t][1] + part[t][2] + part[t][3];
    __syncthreads();

    // epilogue: C/D layout col = lane&15, row = (lane>>4)*4 + reg [m89/m91]
    const int colBase = wc * 64 + (lane & 15);
#pragma unroll
    for (int i = 0; i < 2; ++i) {
        const int rl0 = wr * 32 + i * 16 + (lane >> 4) * 4;
#pragma unroll
        for (int j = 0; j < 4; ++j) {
            const int col = colBase + j * 16;
            const float cj = cs[col];
#pragma unroll
            for (int r = 0; r < 4; ++r) {
                const int rl = rl0 + r;
                out[(rowBase + rl) * K_STATES + col] = acc[i][j][r] + cj - 0.5f * s2row[rl];
            }
        }
    }
#undef LOADP
#undef STAGE
#undef COMPUTE
}

extern "C" void kernel_launch(void* const* d_in, const int* in_sizes, int n_in,
                              void* d_out, int out_size, void* d_ws, size_t ws_size,
                              hipStream_t stream) {
    const float* s     = (const float*)d_in[0];
    const float* means = (const float*)d_in[1];
    const float* var   = (const float*)d_in[2];
    float* out = (float*)d_out;

    unsigned short* mwbf = (unsigned short*)d_ws;
    float* cvec = (float*)((char*)d_ws + (size_t)K_STATES * D_DIM * sizeof(unsigned short));

    prep_kernel<<<K_STATES, 256, 0, stream>>>(means, var, mwbf, cvec);
    dmv_main<<<M_ROWS / BM, 256, 0, stream>>>(s, mwbf, var, cvec, out);
}

// Round 8
// 43.717 us; speedup vs baseline: 1.2120x; 1.1056x over previous
//
#include <hip/hip_runtime.h>
#include <stdint.h>

// Problem dims (fixed by reference)
#define D_DIM    768
#define K_STATES 128
#define M_ROWS   65536      // B*T = 256*256
#define BM       128        // rows per block
#define BK       32         // D-chunk per K-step
#define NSTEPS   (D_DIM / BK)   // 24
#define LDSTRIDE 40         // bf16 elems per LDS row: 80B, 16B-aligned, bank-even

typedef __attribute__((ext_vector_type(8))) short bf16x8;
typedef __attribute__((ext_vector_type(4))) float f32x4;
typedef __attribute__((ext_vector_type(4))) int   i32x4;

__device__ __forceinline__ unsigned short f2bf(float f) {
    union { float f; unsigned u; } x; x.f = f;
    unsigned r = (x.u + 0x7FFFu + ((x.u >> 16) & 1u)) >> 16;   // RNE
    return (unsigned short)r;
}

// ---------------- prep: mw[k][d] = means*inv_var (bf16), c[k] = log_norm - 0.5*m2[k]
__global__ void __launch_bounds__(256) prep_kernel(
        const float* __restrict__ means, const float* __restrict__ var,
        unsigned short* __restrict__ mwbf, float* __restrict__ cvec) {
    const int k = blockIdx.x;
    const int t = threadIdx.x;
    float m2 = 0.f, ld = 0.f;
    for (int d = t; d < D_DIM; d += 256) {
        float v  = var[d];
        float iv = 1.0f / v;
        float m  = means[k * D_DIM + d];
        mwbf[k * D_DIM + d] = f2bf(m * iv);
        m2 += m * m * iv;
        ld += logf(v);
    }
#pragma unroll
    for (int off = 32; off > 0; off >>= 1) {
        m2 += __shfl_down(m2, off, 64);
        ld += __shfl_down(ld, off, 64);
    }
    __shared__ float rm[4], rl[4];
    const int wid = t >> 6;
    if ((t & 63) == 0) { rm[wid] = m2; rl[wid] = ld; }
    __syncthreads();
    if (t == 0) {
        float M2 = rm[0] + rm[1] + rm[2] + rm[3];
        float LD = rl[0] + rl[1] + rl[2] + rl[3];
        cvec[k] = -0.5f * ((float)D_DIM * 1.8378770664093453f + LD + M2);
    }
}

// ---------------- main: out[bt][k] = cross + c[k] - 0.5*s2[bt]
__global__ void __launch_bounds__(256) dmv_main(
        const float* __restrict__ s, const unsigned short* __restrict__ mwbf,
        const float* __restrict__ var, const float* __restrict__ cvec,
        float* __restrict__ out) {
    __shared__ unsigned short As[2][BM * LDSTRIDE];        // 2 x 10.0 KB bf16 s-tile
    __shared__ unsigned short Bs[2][K_STATES * LDSTRIDE];  // 2 x 10.0 KB bf16 mw-tile
    __shared__ float ivs[D_DIM];                           // 3 KB
    __shared__ float part[BM][8];                          // s2 partials
    __shared__ float s2row[BM];
    __shared__ float cs[K_STATES];

    const int t    = threadIdx.x;
    const int lane = t & 63;
    const int w    = t >> 6;
    const int wr   = w >> 1;      // wave row quadrant (0/1)
    const int wc   = w & 1;       // wave col quadrant (0/1)
    const long rowBase = (long)blockIdx.x * BM;

    for (int d = t; d < D_DIM; d += 256) ivs[d] = 1.0f / var[d];
    if (t < K_STATES) cs[t] = cvec[t];

    // staging geometry per K-step:
    // A: 4 rounds, round j: row = j*32 + (t>>3), cols (t&7)*4 .. +3  (f32x4)
    // B: 2 rounds, round j: row = j*64 + (t>>2), cols (t&3)*8 .. +7  (bf16x8 raw)
    const int arow0 = t >> 3;
    const int acol  = (t & 7) * 4;
    const int brow0 = t >> 2;
    const int bcol  = (t & 3) * 8;

    const float*          sA = s    + (rowBase + arow0) * D_DIM + acol;
    const unsigned short* sB = mwbf + brow0 * D_DIM + bcol;

    f32x4 aPref[4];
    i32x4 bPref[2];
    float s2acc[4] = {0.f, 0.f, 0.f, 0.f};

    f32x4 acc[4][4];
#pragma unroll
    for (int i = 0; i < 4; ++i)
#pragma unroll
        for (int j = 0; j < 4; ++j) acc[i][j] = f32x4{0.f, 0.f, 0.f, 0.f};

    auto stageWrite = [&](int buf, int k0) {
#pragma unroll
        for (int j = 0; j < 4; ++j) {
            const int row = j * 32 + arow0;
            f32x4 v = aPref[j];
            s2acc[j] += v[0]*v[0]*ivs[k0+acol+0] + v[1]*v[1]*ivs[k0+acol+1]
                      + v[2]*v[2]*ivs[k0+acol+2] + v[3]*v[3]*ivs[k0+acol+3];
            unsigned u0 = (unsigned)f2bf(v[0]) | ((unsigned)f2bf(v[1]) << 16);
            unsigned u1 = (unsigned)f2bf(v[2]) | ((unsigned)f2bf(v[3]) << 16);
            *reinterpret_cast<uint2*>(&As[buf][row * LDSTRIDE + acol]) = make_uint2(u0, u1);
        }
#pragma unroll
        for (int j = 0; j < 2; ++j) {
            const int row = j * 64 + brow0;
            *reinterpret_cast<i32x4*>(&Bs[buf][row * LDSTRIDE + bcol]) = bPref[j];
        }
    };

    // prologue: global loads for step 0 (no LDS dependence yet)
#pragma unroll
    for (int j = 0; j < 4; ++j) aPref[j] = *(const f32x4*)(sA + (long)j * 32 * D_DIM);
#pragma unroll
    for (int j = 0; j < 2; ++j) bPref[j] = *(const i32x4*)(sB + j * 64 * D_DIM);
    __syncthreads();             // ivs/cs ready
    stageWrite(0, 0);

    const int g  = (lane >> 4) * 8;          // k-offset within BK
    const int rA = wr * 64 + (lane & 15);
    const int rB = wc * 64 + (lane & 15);

    for (int st = 0; st < NSTEPS; ++st) {
        const int cur = st & 1;
        const int k0n = (st + 1) * BK;
        if (st + 1 < NSTEPS) {
#pragma unroll
            for (int j = 0; j < 4; ++j)
                aPref[j] = *(const f32x4*)(sA + (long)j * 32 * D_DIM + k0n);
#pragma unroll
            for (int j = 0; j < 2; ++j)
                bPref[j] = *(const i32x4*)(sB + j * 64 * D_DIM + k0n);
        }
        __syncthreads();         // buf[cur] staged & prior reads drained

        const unsigned short* Ab = &As[cur][0];
        const unsigned short* Bb = &Bs[cur][0];
        bf16x8 afrag[4], bfrag[4];
#pragma unroll
        for (int i = 0; i < 4; ++i)
            afrag[i] = *(const bf16x8*)(Ab + (rA + i * 16) * LDSTRIDE + g);
#pragma unroll
        for (int j = 0; j < 4; ++j)
            bfrag[j] = *(const bf16x8*)(Bb + (rB + j * 16) * LDSTRIDE + g);
#pragma unroll
        for (int i = 0; i < 4; ++i)
#pragma unroll
            for (int j = 0; j < 4; ++j)
                acc[i][j] = __builtin_amdgcn_mfma_f32_16x16x32_bf16(
                                afrag[i], bfrag[j], acc[i][j], 0, 0, 0);

        if (st + 1 < NSTEPS) stageWrite((st + 1) & 1, k0n);
    }

    // s2 reduction: each thread owns rows {j*32 + (t>>3)}, col-slot t&7
#pragma unroll
    for (int j = 0; j < 4; ++j) part[j * 32 + arow0][t & 7] = s2acc[j];
    __syncthreads();
    if (t < BM) {
        float v = 0.f;
#pragma unroll
        for (int sl = 0; sl < 8; ++sl) v += part[t][sl];
        s2row[t] = v;
    }
    __syncthreads();

    // epilogue: C/D layout col = lane&15, row = (lane>>4)*4 + reg  [m89/m91-verified]
    const int colBase = wc * 64 + (lane & 15);
#pragma unroll
    for (int i = 0; i < 4; ++i) {
        const int rl0 = wr * 64 + i * 16 + (lane >> 4) * 4;
#pragma unroll
        for (int j = 0; j < 4; ++j) {
            const int col = colBase + j * 16;
            const float cj = cs[col];
#pragma unroll
            for (int r = 0; r < 4; ++r) {
                const int rl = rl0 + r;
                out[(rowBase + rl) * K_STATES + col] = acc[i][j][r] + cj - 0.5f * s2row[rl];
            }
        }
    }
}

extern "C" void kernel_launch(void* const* d_in, const int* in_sizes, int n_in,
                              void* d_out, int out_size, void* d_ws, size_t ws_size,
                              hipStream_t stream) {
    const float* s     = (const float*)d_in[0];
    const float* means = (const float*)d_in[1];
    const float* var   = (const float*)d_in[2];
    float* out = (float*)d_out;

    unsigned short* mwbf = (unsigned short*)d_ws;
    float* cvec = (float*)((char*)d_ws + (size_t)K_STATES * D_DIM * sizeof(unsigned short));

    prep_kernel<<<K_STATES, 256, 0, stream>>>(means, var, mwbf, cvec);
    dmv_main<<<M_ROWS / BM, 256, 0, stream>>>(s, mwbf, var, cvec, out);
}